// Round 1
// baseline (656.947 us; speedup 1.0000x reference)
//
#include <hip/hip_runtime.h>
#include <math.h>

// global_powermean_pooling, P = 2.0
//   out[g, d] = sqrt( mean_{n : batch[n]==g} x[n, d]^2 ),  empty segment -> 0
// x: [N, 128] fp32, batch: [N] int32 sorted ascending in [0, G)
// Strategy: batch is sorted -> one block per graph, binary-search the segment
// range, stream rows with float4 loads, register accumulate, LDS reduce.
// No atomics, no workspace, fully deterministic.

#define D_FEAT 128
#define DV (D_FEAT / 4)  // 32 float4 per row

__global__ __launch_bounds__(256) void global_powermean_pooling_44126493999223_kernel(
    const float* __restrict__ x,
    const int* __restrict__ batch,
    float* __restrict__ out,
    int N)
{
    const int g    = blockIdx.x;
    const int tid  = threadIdx.x;
    const int fg   = tid & 31;   // which float4 of the 128-wide row
    const int lane = tid >> 5;   // node-lane 0..7

    __shared__ int s_range[2];
    if (tid < 2) {
        // lower_bound(batch, g + tid)
        const int key = g + tid;
        int lo = 0, hi = N;
        while (lo < hi) {
            int mid = (lo + hi) >> 1;
            if (batch[mid] < key) lo = mid + 1; else hi = mid;
        }
        s_range[tid] = lo;
    }
    __syncthreads();
    const int start = s_range[0];
    const int end   = s_range[1];
    const int count = end - start;

    const float4* __restrict__ x4 = (const float4*)x;
    float4 acc = make_float4(0.f, 0.f, 0.f, 0.f);
    // rows start..end-1; 8 node-lanes stride the rows; 32 fgroups cover the row.
    // Wave64 = 2 node-lanes * 32 fgroups -> 1KB contiguous per load instruction.
    for (int r = start + lane; r < end; r += 8) {
        float4 v = x4[(size_t)r * DV + fg];
        acc.x += v.x * v.x;
        acc.y += v.y * v.y;
        acc.z += v.z * v.z;
        acc.w += v.w * v.w;
    }

    __shared__ float4 red[256];
    red[tid] = acc;
    __syncthreads();
    // tree-reduce over the 8 node-lanes (stride 32 in tid space)
    for (int off = 4; off >= 1; off >>= 1) {
        if (lane < off) {
            float4 a = red[tid];
            float4 b = red[tid + off * 32];
            a.x += b.x; a.y += b.y; a.z += b.z; a.w += b.w;
            red[tid] = a;
        }
        __syncthreads();
    }

    if (lane == 0) {
        const float inv = 1.0f / (float)(count > 0 ? count : 1);
        float4 s = red[tid];
        float4 o;
        o.x = sqrtf(s.x * inv);
        o.y = sqrtf(s.y * inv);
        o.z = sqrtf(s.z * inv);
        o.w = sqrtf(s.w * inv);
        ((float4*)out)[(size_t)g * DV + fg] = o;  // 32 threads -> 512B contiguous
    }
}

extern "C" void kernel_launch(void* const* d_in, const int* in_sizes, int n_in,
                              void* d_out, int out_size, void* d_ws, size_t ws_size,
                              hipStream_t stream) {
    const float* x     = (const float*)d_in[0];
    const int*   batch = (const int*)d_in[1];
    float*       out   = (float*)d_out;

    const int N = in_sizes[1];           // 1,000,000 nodes
    const int G = out_size / D_FEAT;     // 4096 graphs

    global_powermean_pooling_44126493999223_kernel<<<G, 256, 0, stream>>>(x, batch, out, N);
}

// Round 2
// 651.371 us; speedup vs baseline: 1.0086x; 1.0086x over previous
//
#include <hip/hip_runtime.h>
#include <math.h>

// global_powermean_pooling, P = 2.0
//   out[g, d] = sqrt( mean_{n : batch[n]==g} x[n, d]^2 ),  empty segment -> 0
// x: [N, 128] fp32, batch: [N] int32 sorted ascending in [0, G)
//
// R1 structure:
//   Kernel A: boundary scatter -> off[g] = lower_bound(batch, g), off[G] = N
//             (stored in d_ws; replaces 4096 per-block binary searches)
//   Kernel B: one block per graph, 4x-unrolled float4 streaming with 4
//             independent accumulators (guaranteed MLP), LDS reduce,
//             sqrt(sum/count) epilogue. No atomics, deterministic.

#define D_FEAT 128
#define DV (D_FEAT / 4)  // 32 float4 per row

// ---- Kernel A: segment offsets ------------------------------------------
__global__ __launch_bounds__(256) void seg_offsets_kernel(
    const int* __restrict__ batch, int* __restrict__ off, int N, int G)
{
    int i = blockIdx.x * blockDim.x + threadIdx.x;
    if (i >= N) return;
    int cur = batch[i];
    if (i == 0) {
        for (int g = 0; g <= cur; ++g) off[g] = 0;   // segments before first id
    } else {
        int prev = batch[i - 1];
        for (int g = prev + 1; g <= cur; ++g) off[g] = i;
    }
    if (i == N - 1) {
        for (int g = cur + 1; g <= G; ++g) off[g] = N;  // trailing empties + off[G]
    }
}

// ---- Kernel B: per-graph power-mean pooling ------------------------------
__global__ __launch_bounds__(256) void global_powermean_pooling_44126493999223_kernel(
    const float* __restrict__ x,
    const int* __restrict__ off,
    float* __restrict__ out)
{
    const int g    = blockIdx.x;
    const int tid  = threadIdx.x;
    const int fg   = tid & 31;   // float4 index within the 128-wide row
    const int lane = tid >> 5;   // node-lane 0..7

    const int start = off[g];
    const int end   = off[g + 1];
    const int count = end - start;

    const float4* __restrict__ x4 = (const float4*)x;

    float4 a0 = make_float4(0.f, 0.f, 0.f, 0.f);
    float4 a1 = a0, a2 = a0, a3 = a0;

    // 4x unrolled: 4 independent 1KB wave-loads in flight per iteration.
    int r = start + lane;
    for (; r + 24 < end; r += 32) {
        float4 v0 = x4[(size_t)(r     ) * DV + fg];
        float4 v1 = x4[(size_t)(r +  8) * DV + fg];
        float4 v2 = x4[(size_t)(r + 16) * DV + fg];
        float4 v3 = x4[(size_t)(r + 24) * DV + fg];
        a0.x += v0.x * v0.x; a0.y += v0.y * v0.y; a0.z += v0.z * v0.z; a0.w += v0.w * v0.w;
        a1.x += v1.x * v1.x; a1.y += v1.y * v1.y; a1.z += v1.z * v1.z; a1.w += v1.w * v1.w;
        a2.x += v2.x * v2.x; a2.y += v2.y * v2.y; a2.z += v2.z * v2.z; a2.w += v2.w * v2.w;
        a3.x += v3.x * v3.x; a3.y += v3.y * v3.y; a3.z += v3.z * v3.z; a3.w += v3.w * v3.w;
    }
    for (; r < end; r += 8) {
        float4 v = x4[(size_t)r * DV + fg];
        a0.x += v.x * v.x; a0.y += v.y * v.y; a0.z += v.z * v.z; a0.w += v.w * v.w;
    }
    a0.x += a1.x + a2.x + a3.x;
    a0.y += a1.y + a2.y + a3.y;
    a0.z += a1.z + a2.z + a3.z;
    a0.w += a1.w + a2.w + a3.w;

    __shared__ float4 red[256];
    red[tid] = a0;
    __syncthreads();
    for (int o = 4; o >= 1; o >>= 1) {
        if (lane < o) {
            float4 a = red[tid];
            float4 b = red[tid + o * 32];
            a.x += b.x; a.y += b.y; a.z += b.z; a.w += b.w;
            red[tid] = a;
        }
        __syncthreads();
    }

    if (lane == 0) {
        const float inv = 1.0f / (float)(count > 0 ? count : 1);
        float4 s = red[tid];
        float4 o;
        o.x = sqrtf(s.x * inv);
        o.y = sqrtf(s.y * inv);
        o.z = sqrtf(s.z * inv);
        o.w = sqrtf(s.w * inv);
        ((float4*)out)[(size_t)g * DV + fg] = o;   // 32 lanes -> 512B contiguous
    }
}

extern "C" void kernel_launch(void* const* d_in, const int* in_sizes, int n_in,
                              void* d_out, int out_size, void* d_ws, size_t ws_size,
                              hipStream_t stream) {
    const float* x     = (const float*)d_in[0];
    const int*   batch = (const int*)d_in[1];
    float*       out   = (float*)d_out;

    const int N = in_sizes[1];           // 1,000,000 nodes
    const int G = out_size / D_FEAT;     // 4096 graphs

    int* off = (int*)d_ws;               // G+1 ints (16.4 KB of the 2 GB ws)

    seg_offsets_kernel<<<(N + 255) / 256, 256, 0, stream>>>(batch, off, N, G);
    global_powermean_pooling_44126493999223_kernel<<<G, 256, 0, stream>>>(x, off, out);
}